// Round 1
// 1167.592 us; speedup vs baseline: 1.0708x; 1.0708x over previous
//
#include <hip/hip_runtime.h>
#include <hip/hip_bf16.h>

typedef unsigned short u16;
typedef unsigned int   u32;

typedef __bf16 bf16x8 __attribute__((ext_vector_type(8)));
typedef float  f32x4  __attribute__((ext_vector_type(4)));

__device__ __forceinline__ bf16x8 as_bf16x8(uint4 u) {
    return __builtin_bit_cast(bf16x8, u);
}

// round-half-up bf16 (cheap, adequate: inputs are well-scaled, no NaN/Inf)
__device__ __forceinline__ u16 bf16r(float f) {
    return (u16)((__float_as_uint(f) + 0x8000u) >> 16);
}
__device__ __forceinline__ u32 pack2(float lo, float hi) {
    u32 a = __float_as_uint(lo) + 0x8000u;
    u32 b = __float_as_uint(hi) + 0x8000u;
    return (a >> 16) | (b & 0xFFFF0000u);
}

// HW packed fp32->bf16 (RNE), 1 instr per 2 floats
__device__ __forceinline__ u32 cvtpk(float lo, float hi) {
    u32 r;
    asm("v_cvt_pk_bf16_f32 %0, %1, %2" : "=v"(r) : "v"(lo), "v"(hi));
    return r;
}
__device__ __forceinline__ bf16x8 wcvt(float4 a, float4 b) {
    uint4 u;
    u.x = cvtpk(a.x, a.y); u.y = cvtpk(a.z, a.w);
    u.z = cvtpk(b.x, b.y); u.w = cvtpk(b.z, b.w);
    return as_bf16x8(u);
}

__device__ __forceinline__ float sigmoidf_(float x) {
    return 1.0f / (1.0f + __expf(-x));
}
__device__ __forceinline__ float tanhf_(float x) {
    float xx = fminf(fmaxf(x, -15.0f), 15.0f);
    float e = __expf(2.0f * xx);
    return (e - 1.0f) / (e + 1.0f);
}

// ---------------------------------------------------------------------------
// prep: repack LSTM weights to bf16, keeping only sections i (0:256),
// g (512:768), o (768:1024) -> rows [s*256+n], k-fast. Also bias sums.
// ---------------------------------------------------------------------------
__global__ __launch_bounds__(256) void prep_kernel(
    const float* __restrict__ W_ih0, const float* __restrict__ b_ih0, const float* __restrict__ b_hh0,
    const float* __restrict__ W_ih1, const float* __restrict__ b_ih1, const float* __restrict__ b_hh1,
    u16* __restrict__ Wb0, u16* __restrict__ Wb1, float* __restrict__ bs0, float* __restrict__ bs1)
{
    int idx = blockIdx.x * 256 + threadIdx.x;
    if (idx < 49152) {                       // Wb0: 3*256*64
        int k = idx & 63, sn = idx >> 6;
        int n = sn & 255, s = sn >> 8;
        int row = (s == 0) ? n : (s == 1 ? 512 + n : 768 + n);
        Wb0[idx] = bf16r(W_ih0[row * 64 + k]);
    } else if (idx < 245760) {               // Wb1: 3*256*256
        int j = idx - 49152;
        int k = j & 255, sn = j >> 8;
        int n = sn & 255, s = sn >> 8;
        int row = (s == 0) ? n : (s == 1 ? 512 + n : 768 + n);
        Wb1[j] = bf16r(W_ih1[row * 256 + k]);
    } else if (idx < 247296) {               // bias sums: 2*768
        int j = idx - 245760;
        int l = j / 768, q = j - l * 768;
        int s = q >> 8, n = q & 255;
        int row = (s == 0) ? n : (s == 1 ? 512 + n : 768 + n);
        if (l == 0) bs0[q] = b_ih0[row] + b_hh0[row];
        else        bs1[q] = b_ih1[row] + b_hh1[row];
    }
}

// ---------------------------------------------------------------------------
// LSTM layer: block = 64 rows x 64 h-cols. 4 waves, wave w covers h-cols
// [n0+16w, +16). 3 MFMA acc sets (i,g,o) x 4 row-subtiles. K = 64 or 256.
// x staged in LDS (pad +8 bf16 -> 2-way max bank aliasing on ds_read_b128).
// W fragments read directly from repacked bf16 weights (L2-resident).
// ---------------------------------------------------------------------------
template<int K, bool IS_L1>
__global__ __launch_bounds__(256) void lstm_kernel(
    const void* __restrict__ xin,   // L0: float[M,64]; L1: bf16 u16[M,256]
    const u16*  __restrict__ Wb,    // [768, K] bf16, sections i,g,o
    const float* __restrict__ bsum, // [768]
    u16*   __restrict__ hout_b,     // bf16 [M,256]
    float* __restrict__ hout_f)     // fp32 [M,256] (L1 only)
{
    constexpr int SP = K + 8;
    __shared__ u16 x_s[64 * SP];
    const int t  = threadIdx.x;
    const int m0 = blockIdx.y * 64;
    const int n0 = blockIdx.x * 64;

    if (!IS_L1) {
        // K=64: thread t loads 16 floats (row t/4, cols (t&3)*16..+16), cvt->bf16
        const float* xf = (const float*)xin;
        int row = t >> 2, seg = t & 3;
        const float* src = xf + (size_t)(m0 + row) * 64 + seg * 16;
        u32 p0 = pack2(src[0],  src[1]);
        u32 p1 = pack2(src[2],  src[3]);
        u32 p2 = pack2(src[4],  src[5]);
        u32 p3 = pack2(src[6],  src[7]);
        u32 p4 = pack2(src[8],  src[9]);
        u32 p5 = pack2(src[10], src[11]);
        u32 p6 = pack2(src[12], src[13]);
        u32 p7 = pack2(src[14], src[15]);
        u16* dst = x_s + row * SP + seg * 16;
        *(uint4*)(dst)     = make_uint4(p0, p1, p2, p3);
        *(uint4*)(dst + 8) = make_uint4(p4, p5, p6, p7);
    } else {
        // K=256: 2 passes, thread t: row = p*32 + t/8, 64B chunk (t&7)*32 elems
        const u16* xb = (const u16*)xin;
        #pragma unroll
        for (int p = 0; p < 2; p++) {
            int row = p * 32 + (t >> 3);
            int seg = t & 7;
            const u16* src = xb + (size_t)(m0 + row) * 256 + seg * 32;
            u16* dst = x_s + row * SP + seg * 32;
            #pragma unroll
            for (int i = 0; i < 4; i++)
                *(uint4*)(dst + i * 8) = *(const uint4*)(src + i * 8);
        }
    }
    __syncthreads();

    const int lane = t & 63, w = t >> 6, quad = lane >> 4, l15 = lane & 15;
    const int n = n0 + w * 16 + l15;

    f32x4 acc[3][4] = {};
    #pragma unroll
    for (int kc = 0; kc < K; kc += 32) {
        bf16x8 b[3];
        #pragma unroll
        for (int s = 0; s < 3; s++)
            b[s] = as_bf16x8(*(const uint4*)(Wb + (size_t)(s * 256 + n) * K + kc + quad * 8));
        #pragma unroll
        for (int mt = 0; mt < 4; mt++) {
            bf16x8 a = as_bf16x8(*(const uint4*)(x_s + (mt * 16 + l15) * SP + kc + quad * 8));
            #pragma unroll
            for (int s = 0; s < 3; s++)
                acc[s][mt] = __builtin_amdgcn_mfma_f32_16x16x32_bf16(a, b[s], acc[s][mt], 0, 0, 0);
        }
    }

    const float bi = bsum[n], bg = bsum[256 + n], bo = bsum[512 + n];
    #pragma unroll
    for (int mt = 0; mt < 4; mt++) {
        #pragma unroll
        for (int r = 0; r < 4; r++) {
            int m = m0 + mt * 16 + quad * 4 + r;
            float vi = acc[0][mt][r] + bi;
            float vg = acc[1][mt][r] + bg;
            float vo = acc[2][mt][r] + bo;
            float c  = sigmoidf_(vi) * tanhf_(vg);
            float h  = sigmoidf_(vo) * tanhf_(c);
            size_t off = (size_t)m * 256 + n;
            if (IS_L1) { hout_f[off] = h; hout_b[off] = bf16r(h); }
            else       { hout_b[off] = bf16r(h); }
        }
    }
}

// ---------------------------------------------------------------------------
// fc1+fc4 fused GEMM: C[512,2048] = flat[512,51200](bf16) @ [W1|W4]^T, split-K=8.
// Block: 128m x 64n, 4 waves as 2m x 2n (wave tile 64m x 32n, acc[4][2]).
// Grid (32,4,8) = 1024 blocks -> 4 blocks/CU (vs 2 before; LDS 32KB*4=128KB).
// A staged async via global_load_lds into linear LDS with XOR-swizzled
// (slot16 ^= row&7) pre-swizzled global source -> conflict-free ds_read_b128.
// All 16 fp32 W float4 loads per K-step hoisted before the stage barrier so
// their HBM latency drains with the staging vmcnt(0); fp32 weights are still
// read exactly once from HBM (4 mb-blocks sharing a slice land on same XCD).
// ---------------------------------------------------------------------------
__global__ __launch_bounds__(256) void fc14_kernel(
    const u16* __restrict__ flat,
    const float* __restrict__ w1, const float* __restrict__ w4,
    float* __restrict__ P)
{
    __shared__ __align__(16) u16 A_s[128 * 128];   // 32 KB, swizzled layout
    const int t  = threadIdx.x;
    const int nb = blockIdx.x;                     // 0..31: 64-col tiles
    const int mb = blockIdx.y, z = blockIdx.z;
    const int m0 = mb * 128;
    const float* W = (nb < 16) ? w1 : w4;
    const int wrow0 = (nb & 15) * 64;

    const int lane = t & 63, w = t >> 6;
    const int quad = lane >> 4, l15 = lane & 15;
    const int wm = w >> 1, wn = w & 1;             // 2x2 wave grid
    const int xk = l15 & 7;

    // staging geometry: call j = w*8+it covers rows 4j..4j+3 (1 KB, lane-linear)
    const int rlo = lane >> 4;                     // row within 4-row call
    const int s16 = lane & 15;                     // 16B slot within row
    const int colA = s16 ^ rlo;                    // it even: row&7 = rlo
    const int colB = s16 ^ (4 | rlo);              // it odd:  row&7 = 4|rlo
    const u16* fsrc = flat + (size_t)(m0 + w * 32 + rlo) * 51200 + (size_t)z * 6400;

    // per-lane weight pointers (nt=0,1), advance 128 floats per K-step
    const float* wb0 = W + (size_t)(wrow0 + wn * 32 +  0 + l15) * 51200 + (size_t)z * 6400 + quad * 8;
    const float* wb1 = W + (size_t)(wrow0 + wn * 32 + 16 + l15) * 51200 + (size_t)z * 6400 + quad * 8;

    f32x4 acc[4][2] = {};

    for (int kg = 0; kg < 50; kg++) {
        const int kk = kg * 128;
        __syncthreads();                           // prev iter's LDS reads done
        // async A stage: 8 global_load_lds x 1KB per wave (source pre-swizzled)
        #pragma unroll
        for (int it = 0; it < 8; it++) {
            const u16* src = fsrc + (size_t)(it * 4) * 51200 + kk
                           + ((it & 1) ? colB : colA) * 8;
            u16* dst = A_s + (w * 8 + it) * 512;
            __builtin_amdgcn_global_load_lds(
                (const __attribute__((address_space(1))) u16*)src,
                (__attribute__((address_space(3))) u16*)dst, 16, 0, 0);
        }
        // hoist ALL weight loads for this K-step (latency hides under barrier)
        float4 wf[4][2][2];
        #pragma unroll
        for (int c = 0; c < 4; c++) {
            wf[c][0][0] = *(const float4*)(wb0 + kk + c * 32);
            wf[c][0][1] = *(const float4*)(wb0 + kk + c * 32 + 4);
            wf[c][1][0] = *(const float4*)(wb1 + kk + c * 32);
            wf[c][1][1] = *(const float4*)(wb1 + kk + c * 32 + 4);
        }
        __syncthreads();                           // vmcnt(0): A + W complete
        #pragma unroll
        for (int c = 0; c < 4; c++) {
            bf16x8 b0 = wcvt(wf[c][0][0], wf[c][0][1]);
            bf16x8 b1 = wcvt(wf[c][1][0], wf[c][1][1]);
            const int soff = ((c * 4 + quad) ^ xk) * 8;   // swizzled 16B slot
            #pragma unroll
            for (int mt = 0; mt < 4; mt++) {
                const int row = wm * 64 + mt * 16 + l15;
                bf16x8 a = as_bf16x8(*(const uint4*)(A_s + row * 128 + soff));
                acc[mt][0] = __builtin_amdgcn_mfma_f32_16x16x32_bf16(a, b0, acc[mt][0], 0, 0, 0);
                acc[mt][1] = __builtin_amdgcn_mfma_f32_16x16x32_bf16(a, b1, acc[mt][1], 0, 0, 0);
            }
        }
    }

    float* Pp = P + (size_t)z * (512 * 2048);
    #pragma unroll
    for (int mt = 0; mt < 4; mt++) {
        #pragma unroll
        for (int nt = 0; nt < 2; nt++) {
            const int ng = nb * 64 + wn * 32 + nt * 16 + l15;
            #pragma unroll
            for (int r = 0; r < 4; r++) {
                const int m = m0 + wm * 64 + mt * 16 + quad * 4 + r;
                Pp[(size_t)m * 2048 + ng] = acc[mt][nt][r];
            }
        }
    }
}

// ---------------------------------------------------------------------------
// reduce split-K partials + bias + relu -> c1r[512][2048] (c1 | r)
// ---------------------------------------------------------------------------
__global__ __launch_bounds__(256) void reduce_bias_relu(
    const float* __restrict__ P, const float* __restrict__ b1, const float* __restrict__ b4,
    float* __restrict__ c1r)
{
    int idx = blockIdx.x * 256 + threadIdx.x;   // 0 .. 262143
    int m = idx >> 9;
    int n = (idx & 511) * 4;
    float4 s = make_float4(0.f, 0.f, 0.f, 0.f);
    #pragma unroll
    for (int z = 0; z < 8; z++) {
        float4 p = *(const float4*)(P + ((size_t)z * 512 + m) * 2048 + n);
        s.x += p.x; s.y += p.y; s.z += p.z; s.w += p.w;
    }
    const float* bp = (n < 1024) ? (b1 + n) : (b4 + (n - 1024));
    float4 b = *(const float4*)bp;
    s.x = fmaxf(s.x + b.x, 0.f);
    s.y = fmaxf(s.y + b.y, 0.f);
    s.z = fmaxf(s.z + b.z, 0.f);
    s.w = fmaxf(s.w + b.w, 0.f);
    *(float4*)(c1r + (size_t)m * 2048 + n) = s;
}

// ---------------------------------------------------------------------------
// small fp32 GEMM: out[m,n] = (relu?)(A[m,:K] . W[n,:K] + bias[n])
// block = 16m x 16n threads; A chunk staged in LDS (broadcast reads).
// ---------------------------------------------------------------------------
__global__ __launch_bounds__(256) void sgemm_small(
    const float* __restrict__ A, int lda,
    const float* __restrict__ W,
    const float* __restrict__ bias,
    float* __restrict__ out, int ldo,
    int M, int N, int K, int do_relu)
{
    __shared__ float As[16 * 260];
    const int t = threadIdx.x;
    const int m0 = blockIdx.y * 16, n0 = blockIdx.x * 16;
    const int mi = t >> 4, ni = t & 15;
    const int n = n0 + ni;
    const bool act = n < N;
    float acc = 0.f;
    for (int kc = 0; kc < K; kc += 256) {
        __syncthreads();
        {
            int row = t >> 4, cb = (t & 15) * 16;
            const float* src = A + (size_t)(m0 + row) * lda + kc + cb;
            float* dst = As + row * 260 + cb;
            *(float4*)(dst)      = *(const float4*)(src);
            *(float4*)(dst + 4)  = *(const float4*)(src + 4);
            *(float4*)(dst + 8)  = *(const float4*)(src + 8);
            *(float4*)(dst + 12) = *(const float4*)(src + 12);
        }
        __syncthreads();
        if (act) {
            const float* wr = W + (size_t)n * K + kc;
            const float* ar = As + mi * 260;
            #pragma unroll 4
            for (int k = 0; k < 256; k += 4) {
                float4 w4 = *(const float4*)(wr + k);
                float4 a4 = *(const float4*)(ar + k);
                acc += a4.x * w4.x + a4.y * w4.y + a4.z * w4.z + a4.w * w4.w;
            }
        }
    }
    if (act) {
        float v = acc + bias[n];
        if (do_relu) v = fmaxf(v, 0.f);
        out[(size_t)(m0 + mi) * ldo + n] = v;
    }
}

// ---------------------------------------------------------------------------
// launch
// ---------------------------------------------------------------------------
extern "C" void kernel_launch(void* const* d_in, const int* in_sizes, int n_in,
                              void* d_out, int out_size, void* d_ws, size_t ws_size,
                              hipStream_t stream) {
    const float* x      = (const float*)d_in[0];
    const float* W_ih0  = (const float*)d_in[1];
    const float* b_ih0  = (const float*)d_in[2];
    const float* b_hh0  = (const float*)d_in[3];
    const float* W_ih1  = (const float*)d_in[4];
    const float* b_ih1  = (const float*)d_in[5];
    const float* b_hh1  = (const float*)d_in[6];
    const float* fc1_w  = (const float*)d_in[7];
    const float* fc1_b  = (const float*)d_in[8];
    const float* fc2_w  = (const float*)d_in[9];
    const float* fc2_b  = (const float*)d_in[10];
    const float* fc3_w  = (const float*)d_in[11];
    const float* fc3_b  = (const float*)d_in[12];
    const float* fc4_w  = (const float*)d_in[13];
    const float* fc4_b  = (const float*)d_in[14];
    const float* fc5_w  = (const float*)d_in[15];
    const float* fc5_b  = (const float*)d_in[16];
    float* out = (float*)d_out;

    // workspace layout (bytes); P aliases h0 (dead after lstm1)
    char* ws = (char*)d_ws;
    u16*   Wb0  = (u16*)  (ws + 0);          //   98,304
    u16*   Wb1  = (u16*)  (ws + 98304);      //  393,216
    float* bs0  = (float*)(ws + 491520);     //    3,072
    float* bs1  = (float*)(ws + 494592);     //    3,072
    u16*   h0   = (u16*)  (ws + 524288);     // 52,428,800 (bf16 [102400,256])
    float* P    = (float*)(ws + 524288);     // 33,554,432 (aliases h0)
    u16*   flat = (u16*)  (ws + 52953088);   // 52,428,800 (bf16 [512,51200])
    float* c1r  = (float*)(ws + 105381888);  //  4,194,304 (fp32 [512,2048])
    float* c2   = (float*)(ws + 109576192);  //    524,288 (fp32 [512,256])
    if (ws_size < 110100480) return;         // need ~105 MB

    prep_kernel<<<966, 256, 0, stream>>>(W_ih0, b_ih0, b_hh0, W_ih1, b_ih1, b_hh1,
                                         Wb0, Wb1, bs0, bs1);
    lstm_kernel<64,  false><<<dim3(4, 1600), 256, 0, stream>>>(x,  Wb0, bs0, h0,   nullptr);
    lstm_kernel<256, true ><<<dim3(4, 1600), 256, 0, stream>>>(h0, Wb1, bs1, flat, out);
    fc14_kernel<<<dim3(32, 4, 8), 256, 0, stream>>>(flat, fc1_w, fc4_w, P);
    reduce_bias_relu<<<1024, 256, 0, stream>>>(P, fc1_b, fc4_b, c1r);
    sgemm_small<<<dim3(16, 32), 256, 0, stream>>>(c1r,        2048, fc2_w, fc2_b, c2,             256, 512, 256, 1024, 1);
    sgemm_small<<<dim3(13, 32), 256, 0, stream>>>(c1r + 1024, 2048, fc5_w, fc5_b, out + 26219520, 200, 512, 200, 1024, 0);
    sgemm_small<<<dim3(1,  32), 256, 0, stream>>>(c2,          256, fc3_w, fc3_b, out + 26214400,  10, 512,  10,  256, 0);
}